// Round 7
// baseline (218.931 us; speedup 1.0000x reference)
//
#include <hip/hip_runtime.h>
#include <hip/hip_bf16.h>

#define B_ 4
#define T_ 4096
#define C_ 1024
#define H_ 64

typedef __bf16 bf16x8 __attribute__((ext_vector_type(8)));
typedef float f32x4 __attribute__((ext_vector_type(4)));
typedef unsigned short u16x8 __attribute__((ext_vector_type(8)));

union Frag8 { uint4 u; bf16x8 b; u16x8 s; };

__device__ inline unsigned short bfbits(float f) {
  union { __hip_bfloat16 h; unsigned short u; } cv;
  cv.h = __float2bfloat16(f);
  return cv.u;
}

__device__ inline float b2f(unsigned u) {
  union { unsigned i; float f; } c; c.i = u << 16; return c.f;
}

__device__ inline bf16x8 ldb8(const unsigned short* p) {
  Frag8 f; f.u = *(const uint4*)p; return f.b;
}

// pack two fp32 -> (bf16(a)) | (bf16(b)<<16), round-half-up, 3 VALU ops
__device__ inline unsigned pkbf(float a, float b) {
  union { float f; unsigned u; } ua, ub; ua.f = a; ub.f = b;
  return __builtin_amdgcn_perm(ub.u + 0x8000u, ua.u + 0x8000u, 0x07060302u);
}

__device__ inline Frag8 packA(float4 a0, float4 a1) {
  Frag8 af;
  af.s[0] = bfbits(a0.x); af.s[1] = bfbits(a0.y);
  af.s[2] = bfbits(a0.z); af.s[3] = bfbits(a0.w);
  af.s[4] = bfbits(a1.x); af.s[5] = bfbits(a1.y);
  af.s[6] = bfbits(a1.z); af.s[7] = bfbits(a1.w);
  return af;
}

// async global->LDS, 16B per lane; LDS dest = wave-uniform base + lane*16
__device__ inline void gload16(const void* g, void* l) {
  __builtin_amdgcn_global_load_lds(
      (const __attribute__((address_space(1))) unsigned int*)g,
      (__attribute__((address_space(3))) unsigned int*)l, 16, 0, 0);
}

// ---------------- k0: convert W (3 x [64,1024] fp32) to bf16 ----------------
__global__ __launch_bounds__(256) void wconv(const float* __restrict__ Wq,
                                             const float* __restrict__ Wk,
                                             const float* __restrict__ Wv,
                                             unsigned short* __restrict__ Wb) {
  int i = blockIdx.x * 256 + threadIdx.x;
  size_t e = (size_t)i * 4;
  const float* src = (e < 65536) ? (Wq + e)
                   : (e < 131072 ? (Wk + (e - 65536)) : (Wv + (e - 131072)));
  float4 v = *(const float4*)src;
  unsigned long long o =
      (unsigned long long)bfbits(v.x)
    | ((unsigned long long)bfbits(v.y) << 16)
    | ((unsigned long long)bfbits(v.z) << 32)
    | ((unsigned long long)bfbits(v.w) << 48);
  *(unsigned long long*)(Wb + e) = o;
}

// ---------------- k1: QKV projection GEMM, 2-phase double-buffered ----------
__global__ __launch_bounds__(256) void qkv_proj(const float* __restrict__ x,
                                                const unsigned short* __restrict__ Wb,
                                                unsigned short* __restrict__ qkv,
                                                unsigned short* __restrict__ Vt) {
  __shared__ float xs[2][2048];               // 2 x (32 rows x 64 f32) = 16 KB
  __shared__ unsigned short Wsh[2][12288];    // 2 x (192 rows x 64 halves) = 48 KB
  const int lane = threadIdx.x & 63;
  const int wave = threadIdx.x >> 6;
  const int q16 = lane & 15, quad = lane >> 4;
  const int x7 = q16 & 7;
  const size_t row0 = (size_t)blockIdx.x * 32;

  const int sr = lane >> 4;                  // x-staging: row within group of 4
  const int sc_pos = lane & 15;              // x-staging: stored 16B-chunk pos
  const int rloc = lane >> 3;                // W-staging: row within group of 8
  const int cpos = lane & 7;                 // W-staging: stored 16B-chunk pos

  f32x4 acc[2][3] = {};

  auto stage = [&](int buf, int kc) {
#pragma unroll
    for (int ii = 0; ii < 2; ++ii) {
      int i = wave * 2 + ii;
      int r = i * 4 + sr;
      int sg = (sc_pos >> 1) ^ (r & 7);
      const float* gp = x + (row0 + r) * C_ + kc + sg * 8 + (sc_pos & 1) * 4;
      gload16(gp, &xs[buf][i * 256]);
    }
#pragma unroll
    for (int jj = 0; jj < 6; ++jj) {
      int j = wave * 6 + jj;
      int g = j * 8 + rloc;                  // flat col 0..191
      const unsigned short* gp = Wb + (size_t)(g >> 6) * 65536
                                    + (size_t)(g & 63) * C_ + kc + (cpos ^ rloc) * 8;
      gload16(gp, &Wsh[buf][j * 512]);
    }
  };

  stage(0, 0);
  __syncthreads();                           // prologue staging visible

  int cur = 0;
  for (int t = 0; t < 16; ++t) {
    if (t < 15) stage(cur ^ 1, (t + 1) * 64);  // prefetch next chunk
    const float* Xc = xs[cur];
    const unsigned short* Wc = Wsh[cur];
#pragma unroll
    for (int s = 0; s < 2; ++s) {
      bf16x8 bf[3];
#pragma unroll
      for (int ct = 0; ct < 3; ++ct) {
        int g = wave * 48 + ct * 16 + q16;
        bf[ct] = ldb8(&Wc[g * 64 + (((s * 4 + quad) ^ x7) * 8)]);
      }
#pragma unroll
      for (int rt = 0; rt < 2; ++rt) {
        int r = rt * 16 + q16;
        int p = ((s * 4 + quad) ^ (r & 7)) * 8;
        const float* ap = &Xc[r * 64 + p];
        float4 a0 = *(const float4*)ap;
        float4 a1 = *(const float4*)(ap + 4);
        Frag8 af = packA(a0, a1);
#pragma unroll
        for (int ct = 0; ct < 3; ++ct)
          acc[rt][ct] = __builtin_amdgcn_mfma_f32_16x16x32_bf16(
              af.b, bf[ct], acc[rt][ct], 0, 0, 0);
      }
    }
    __syncthreads();                         // readers done + next stage landed
    cur ^= 1;
  }

  const int bb = (int)(blockIdx.x >> 7);     // 128 blocks per batch
#pragma unroll
  for (int rt = 0; rt < 2; ++rt) {
    const int t0 = (int)(row0 - (size_t)bb * T_) + rt * 16 + quad * 4;
#pragma unroll
    for (int ct = 0; ct < 3; ++ct) {
      int gcol = wave * 48 + ct * 16;
      int mat = gcol >> 6, h = (gcol & 63) + q16;
      if (mat == 2) {                        // V: store transposed
        ushort4 v;
        v.x = bfbits(acc[rt][ct][0]); v.y = bfbits(acc[rt][ct][1]);
        v.z = bfbits(acc[rt][ct][2]); v.w = bfbits(acc[rt][ct][3]);
        *(ushort4*)(Vt + ((size_t)bb * H_ + h) * T_ + t0) = v;
      } else {
        // Q pre-scaled by (1/sqrt(64))*log2(e) -> softmax in exp2 domain
        float scale = (mat == 0) ? 0.18033688f : 1.0f;
#pragma unroll
        for (int r = 0; r < 4; ++r) {
          size_t row = row0 + rt * 16 + quad * 4 + r;
          qkv[(size_t)mat * 1048576 + row * H_ + h] = bfbits(acc[rt][ct][r] * scale);
        }
      }
    }
  }
}

// ---------------- k2: flash attention, NO LDS / NO BARRIERS -----------------
// grid (256, ny): x -> (b, 64-row q-band g reversed), y = k-chunk of (1<<lgch)
// 64-col tiles. Block = 4 independent waves; wave w owns 16 q-rows
// (qtl = g*4 + w). K/V are L2-resident (0.5 MB each per batch) and fragment
// addresses are wave-independent, so L1 serves the cross-wave repeats --
// LDS staging was pure overhead (catalog m169). Each wave loads its K/V
// fragments directly from global (contiguous 16B loads; the psi permutation
// of R5/R6 folded into the global row index), computes, proceeds. Zero
// __syncthreads, zero vmcnt(0) drains, LDS=0 -> occupancy VGPR-bound only.
// O^T formulation (zero-shuffle PV) + defer-max kept from R5.
__global__ __launch_bounds__(256) void attn(const unsigned short* __restrict__ Q,
                                            const unsigned short* __restrict__ K,
                                            const unsigned short* __restrict__ Vt,
                                            float* __restrict__ part,
                                            int lgch, int nslots) {
  const int b = blockIdx.x >> 6;
  const int g = 63 - (blockIdx.x & 63);      // 64-row q-band, big first
  const int ki = g + 1;                      // causal 64-col tiles for band
  const int c = blockIdx.y;
  const int cst = c << lgch;
  if (cst >= ki) return;                     // uniform across the block
  const int tcnt = 1 << lgch;
  const int kend = (ki < cst + tcnt) ? ki : cst + tcnt;

  const int lane = threadIdx.x & 63;
  const int wave = threadIdx.x >> 6;         // 0..3
  const int q16 = lane & 15, quad = lane >> 4;

  const unsigned short* Qb = Q + (size_t)b * T_ * H_;
  const unsigned short* Kb = K + (size_t)b * T_ * H_;
  const unsigned short* Vtb = Vt + (size_t)b * H_ * T_;

  const int qtl = g * 4 + wave;              // 16-row q-tile, 0..255
  const int q_abs = qtl * 16 + q16;

  // K row (within tile) this lane's A-fragment needs for kb:
  //   kbase + 4*(kb&1) + 32*(kb>>1)   (psi permutation, validated R5/R6)
  const int kbase = 8 * (q16 >> 2) + (q16 & 3);

  bf16x8 qf0 = ldb8(Qb + (size_t)(qtl * 16 + q16) * H_ + quad * 8);
  bf16x8 qf1 = ldb8(Qb + (size_t)(qtl * 16 + q16) * H_ + 32 + quad * 8);

  f32x4 o[4] = {};                           // O^T frag: h=ct*16+quad*4+r, q=q16
  float m = -3.0e38f, l = 0.0f;              // per-lane l partial (this quad)

  for (int kt = cst; kt < kend; ++kt) {
    const int kkb = kt * 64;

    // ---- direct K fragment loads (16B each, L1/L2-hot) ----
    const unsigned short* Ktile = Kb + (size_t)kkb * H_ + quad * 8;
    bf16x8 ka[4][2];
#pragma unroll
    for (int kb = 0; kb < 4; ++kb) {
      const unsigned short* kr =
          Ktile + (size_t)(kbase + 4 * (kb & 1) + 32 * (kb >> 1)) * H_;
      ka[kb][0] = ldb8(kr);
      ka[kb][1] = ldb8(kr + 32);
    }
    // ---- direct V fragment loads (issued early; overlap QK^T/softmax) ----
    const unsigned short* Vtile = Vtb + kkb + quad * 8;
    bf16x8 vf[2][4];
#pragma unroll
    for (int ks = 0; ks < 2; ++ks)
#pragma unroll
      for (int ct = 0; ct < 4; ++ct)
        vf[ks][ct] = ldb8(Vtile + (size_t)(q16 + 16 * ct) * T_ + ks * 32);

    // ---- QK^T: S^T = K Q^T ----
    f32x4 st[4];
#pragma unroll
    for (int kb = 0; kb < 4; ++kb) {
      f32x4 s = {0.f, 0.f, 0.f, 0.f};
      s = __builtin_amdgcn_mfma_f32_16x16x32_bf16(ka[kb][0], qf0, s, 0, 0, 0);
      s = __builtin_amdgcn_mfma_f32_16x16x32_bf16(ka[kb][1], qf1, s, 0, 0, 0);
      st[kb] = s;
    }
    if (kt == ki - 1) {                      // diagonal tile: causal mask
      const int kb8q = kkb + 8 * quad;       // st[kb][r] <-> k = kb8q+4(kb&1)+32(kb>>1)+r
#pragma unroll
      for (int kb = 0; kb < 4; ++kb) {
        const int kof = kb8q + 4 * (kb & 1) + 32 * (kb >> 1);
#pragma unroll
        for (int r = 0; r < 4; ++r)
          if (kof + r > q_abs) st[kb][r] = -3.0e38f;
      }
    }

    // ---- online softmax (exp2 domain, defer-max, per-lane l partials) ----
    float mloc = fmaxf(fmaxf(st[0][0], st[0][1]), fmaxf(st[0][2], st[0][3]));
#pragma unroll
    for (int kb = 1; kb < 4; ++kb)
      mloc = fmaxf(mloc, fmaxf(fmaxf(st[kb][0], st[kb][1]),
                               fmaxf(st[kb][2], st[kb][3])));
    mloc = fmaxf(mloc, __shfl_xor(mloc, 16));
    mloc = fmaxf(mloc, __shfl_xor(mloc, 32));
    const bool defer = __all(mloc - m <= 8.0f);   // wave-uniform
    const float mnew = defer ? m : fmaxf(m, mloc);
    float lsum = 0.f;
    unsigned pk[4][2];
#pragma unroll
    for (int kb = 0; kb < 4; ++kb) {
      float p0 = exp2f(st[kb][0] - mnew);
      float p1 = exp2f(st[kb][1] - mnew);
      float p2 = exp2f(st[kb][2] - mnew);
      float p3 = exp2f(st[kb][3] - mnew);
      lsum += (p0 + p1) + (p2 + p3);
      pk[kb][0] = pkbf(p0, p1);
      pk[kb][1] = pkbf(p2, p3);
    }
    if (defer) {
      l += lsum;                             // alpha == 1, no rescale
    } else {
      float alpha = exp2f(m - mnew);         // per-lane (col=q16 layout)
      l = l * alpha + lsum;
      m = mnew;
#pragma unroll
      for (int ct = 0; ct < 4; ++ct) {
        o[ct][0] *= alpha; o[ct][1] *= alpha;
        o[ct][2] *= alpha; o[ct][3] *= alpha;
      }
    }

    // ---- PV: O^T += V^T P^T; P^T B-frag lane-local (zero shuffles) ----
#pragma unroll
    for (int ks = 0; ks < 2; ++ks) {
      Frag8 pf;
      pf.u.x = pk[2 * ks][0];
      pf.u.y = pk[2 * ks][1];
      pf.u.z = pk[2 * ks + 1][0];
      pf.u.w = pk[2 * ks + 1][1];
      o[0] = __builtin_amdgcn_mfma_f32_16x16x32_bf16(vf[ks][0], pf.b, o[0], 0, 0, 0);
      o[1] = __builtin_amdgcn_mfma_f32_16x16x32_bf16(vf[ks][1], pf.b, o[1], 0, 0, 0);
      o[2] = __builtin_amdgcn_mfma_f32_16x16x32_bf16(vf[ks][2], pf.b, o[2], 0, 0, 0);
      o[3] = __builtin_amdgcn_mfma_f32_16x16x32_bf16(vf[ks][3], pf.b, o[3], 0, 0, 0);
    }
  }

  // ---- partial write: O^T pairs; word (ct*64+lane)*2+p packs h=..2p,2p+1 ----
  float lr = l;
  lr += __shfl_xor(lr, 16);
  lr += __shfl_xor(lr, 32);
  float* Pf = part + ((size_t)((b << 8) + qtl) * nslots + c) * 544;
  unsigned* Pw = (unsigned*)Pf;
#pragma unroll
  for (int ct = 0; ct < 4; ++ct) {
    uint2 w;
    w.x = pkbf(o[ct][0], o[ct][1]);
    w.y = pkbf(o[ct][2], o[ct][3]);
    *(uint2*)&Pw[(ct * 64 + lane) * 2] = w;
  }
  if (quad == 0) { Pf[512 + q16] = m; Pf[528 + q16] = lr; }
}

// ---------------- k3: merge partials per q-tile, normalize, store ----------
// Partial O^T layout: word (ct*64 + quad*16 + q)*2 + p = bf16 pair
// (h = ct*16+quad*4+2p, h+1), col q. Thread -> (q=row, h=col0..col0+3).
__global__ __launch_bounds__(256) void attn_merge(const float* __restrict__ part,
                                                  float* __restrict__ out,
                                                  int lgch, int nslots) {
  const int qt = blockIdx.x;                 // 0..1023
  const int qtl = qt & 255, b = qt >> 8;
  const int ki = (qtl >> 2) + 1;             // 64-row k-tiles
  const int nch = (ki + (1 << lgch) - 1) >> lgch;
  const int t = threadIdx.x;
  const int row = t >> 4;                    // q 0..15
  const int col0 = (t & 15) * 4;             // h base
  const int ct = col0 >> 4;
  const int quad_s = (col0 >> 2) & 3;
  const int lane0 = quad_s * 16 + row;
  const float* P0 = part + (size_t)qt * nslots * 544;
  float M = -3.0e38f;
  for (int c2 = 0; c2 < nch; ++c2) M = fmaxf(M, P0[c2 * 544 + 512 + row]);
  float L = 0.f;
  float ax = 0.f, ay = 0.f, az = 0.f, aw = 0.f;
  for (int c2 = 0; c2 < nch; ++c2) {
    const float* P = P0 + c2 * 544;
    float wgt = exp2f(P[512 + row] - M);
    L += wgt * P[528 + row];
    const unsigned* Pww = (const unsigned*)P;
    uint2 wd = *(const uint2*)&Pww[(ct * 64 + lane0) * 2];
    ax += wgt * b2f(wd.x & 0xffffu);
    ay += wgt * b2f(wd.x >> 16);
    az += wgt * b2f(wd.y & 0xffffu);
    aw += wgt * b2f(wd.y >> 16);
  }
  float inv = 1.0f / L;
  float4 r = {ax * inv, ay * inv, az * inv, aw * inv};
  *(float4*)(out + ((size_t)b * T_ + qtl * 16 + row) * H_ + col0) = r;
}

extern "C" void kernel_launch(void* const* d_in, const int* in_sizes, int n_in,
                              void* d_out, int out_size, void* d_ws, size_t ws_size,
                              hipStream_t stream) {
  const float* x  = (const float*)d_in[0];
  const float* Wq = (const float*)d_in[1];
  const float* Wk = (const float*)d_in[2];
  const float* Wv = (const float*)d_in[3];
  float* out = (float*)d_out;
  unsigned short* ws = (unsigned short*)d_ws;

  // ws layout (ushort units):
  //   [0, 196608)           Wb  (Q|K|V bf16 weights)
  //   [196608, +2*1048576)  Q,K bf16 [B*T][64]  (Q pre-scaled, exp2 domain)
  //   next 1048576          Vt bf16 [B][64][T]
  //   next (float region)   partials: 1024 * nslots * 544 fp32 words
  unsigned short* Wb  = ws;
  unsigned short* qkv = ws + 196608;
  unsigned short* Vt  = qkv + (size_t)2 * 1048576;
  float* part = (float*)(ws + 196608 + (size_t)3 * 1048576);

  // chunk = 4 tiles (16 y-chunks, 35.7 MB partials) if workspace allows,
  // else the chunk = 8 layout (17.8 MB partials).
  const size_t base_bytes = ((size_t)196608 + (size_t)3 * 1048576) * 2;
  const size_t need16 = base_bytes + (size_t)1024 * 16 * 544 * 4;
  int lgch = 3, ny = 8, nslots = 8;
  if (ws_size >= need16) { lgch = 2; ny = 16; nslots = 16; }

  wconv<<<192, 256, 0, stream>>>(Wq, Wk, Wv, Wb);
  qkv_proj<<<512, 256, 0, stream>>>(x, Wb, qkv, Vt);
  attn<<<dim3(256, ny), 256, 0, stream>>>(qkv, qkv + 1048576, Vt, part, lgch, nslots);
  attn_merge<<<1024, 256, 0, stream>>>(part, out, lgch, nslots);
}

// Round 8
// 198.982 us; speedup vs baseline: 1.1003x; 1.1003x over previous
//
#include <hip/hip_runtime.h>
#include <hip/hip_bf16.h>

#define B_ 4
#define T_ 4096
#define C_ 1024
#define H_ 64

typedef __bf16 bf16x8 __attribute__((ext_vector_type(8)));
typedef float f32x4 __attribute__((ext_vector_type(4)));
typedef unsigned short u16x8 __attribute__((ext_vector_type(8)));

union Frag8 { uint4 u; bf16x8 b; u16x8 s; };

__device__ inline unsigned short bfbits(float f) {
  union { __hip_bfloat16 h; unsigned short u; } cv;
  cv.h = __float2bfloat16(f);
  return cv.u;
}

__device__ inline float b2f(unsigned u) {
  union { unsigned i; float f; } c; c.i = u << 16; return c.f;
}

__device__ inline bf16x8 ldb8(const unsigned short* p) {
  Frag8 f; f.u = *(const uint4*)p; return f.b;
}

// pack two fp32 -> (bf16(a)) | (bf16(b)<<16), round-half-up, 3 VALU ops
__device__ inline unsigned pkbf(float a, float b) {
  union { float f; unsigned u; } ua, ub; ua.f = a; ub.f = b;
  return __builtin_amdgcn_perm(ub.u + 0x8000u, ua.u + 0x8000u, 0x07060302u);
}

__device__ inline Frag8 packA(float4 a0, float4 a1) {
  Frag8 af;
  af.s[0] = bfbits(a0.x); af.s[1] = bfbits(a0.y);
  af.s[2] = bfbits(a0.z); af.s[3] = bfbits(a0.w);
  af.s[4] = bfbits(a1.x); af.s[5] = bfbits(a1.y);
  af.s[6] = bfbits(a1.z); af.s[7] = bfbits(a1.w);
  return af;
}

// async global->LDS, 16B per lane; LDS dest = wave-uniform base + lane*16
__device__ inline void gload16(const void* g, void* l) {
  __builtin_amdgcn_global_load_lds(
      (const __attribute__((address_space(1))) unsigned int*)g,
      (__attribute__((address_space(3))) unsigned int*)l, 16, 0, 0);
}

// ---------------- k0: convert W (3 x [64,1024] fp32) to bf16 ----------------
__global__ __launch_bounds__(256) void wconv(const float* __restrict__ Wq,
                                             const float* __restrict__ Wk,
                                             const float* __restrict__ Wv,
                                             unsigned short* __restrict__ Wb) {
  int i = blockIdx.x * 256 + threadIdx.x;
  size_t e = (size_t)i * 4;
  const float* src = (e < 65536) ? (Wq + e)
                   : (e < 131072 ? (Wk + (e - 65536)) : (Wv + (e - 131072)));
  float4 v = *(const float4*)src;
  unsigned long long o =
      (unsigned long long)bfbits(v.x)
    | ((unsigned long long)bfbits(v.y) << 16)
    | ((unsigned long long)bfbits(v.z) << 32)
    | ((unsigned long long)bfbits(v.w) << 48);
  *(unsigned long long*)(Wb + e) = o;
}

// ---------------- k1: QKV projection, per-matrix blocks, 32 KB LDS ----------
// Block = 32 rows x 64 cols of ONE matrix (mat = blockIdx.x % 3, fastest-
// varying so the 3 blocks sharing an x row-tile are dispatch-adjacent and
// share x through L2/L3). LDS: x dbuf 16 KB + W dbuf 16 KB = 32 KB ->
// 5 blocks/CU (was 64 KB -> 2 blocks/CU: THE occupancy binder). 2-phase
// double-buffered staging as validated in R1-R7; per-wave: 1 col-frag x
// 2 row-frags = 4 MFMA/K-step.
__global__ __launch_bounds__(256) void qkv_proj(const float* __restrict__ x,
                                                const unsigned short* __restrict__ Wb,
                                                unsigned short* __restrict__ qkv,
                                                unsigned short* __restrict__ Vt) {
  __shared__ float xs[2][2048];               // 2 x (32 rows x 64 f32) = 16 KB
  __shared__ unsigned short Wsh[2][4096];     // 2 x (64 rows x 64 halves) = 16 KB
  const int lane = threadIdx.x & 63;
  const int wave = threadIdx.x >> 6;
  const int q16 = lane & 15, quad = lane >> 4;
  const int x7 = q16 & 7;
  const int mat  = (int)(blockIdx.x % 3);
  const int rblk = (int)(blockIdx.x / 3);    // 0..511
  const size_t row0 = (size_t)rblk * 32;

  const int sr = lane >> 4;                  // x-staging: row within group of 4
  const int sc_pos = lane & 15;              // x-staging: stored 16B-chunk pos
  const int rloc = lane >> 3;                // W-staging: row within group of 8
  const int cpos = lane & 7;                 // W-staging: stored 16B-chunk pos

  const unsigned short* Wm = Wb + (size_t)mat * 65536;

  f32x4 acc[2] = {};

  auto stage = [&](int buf, int kc) {
    // ---- stage x: 8 issues (2/wave), rows i*4+sr, 32B-superchunk swizzle ---
#pragma unroll
    for (int ii = 0; ii < 2; ++ii) {
      int i = wave * 2 + ii;
      int r = i * 4 + sr;
      int sg = (sc_pos >> 1) ^ (r & 7);
      const float* gp = x + (row0 + r) * C_ + kc + sg * 8 + (sc_pos & 1) * 4;
      gload16(gp, &xs[buf][i * 256]);
    }
    // ---- stage W (one matrix): 8 issues (2/wave), rows 8j+rloc ----
#pragma unroll
    for (int jj = 0; jj < 2; ++jj) {
      int j = wave * 2 + jj;
      int g = j * 8 + rloc;                  // output col 0..63
      const unsigned short* gp = Wm + (size_t)g * C_ + kc + (cpos ^ rloc) * 8;
      gload16(gp, &Wsh[buf][j * 512]);
    }
  };

  stage(0, 0);
  __syncthreads();                           // prologue staging visible

  int cur = 0;
  for (int t = 0; t < 16; ++t) {
    if (t < 15) stage(cur ^ 1, (t + 1) * 64);  // prefetch next chunk
    const float* Xc = xs[cur];
    const unsigned short* Wc = Wsh[cur];
#pragma unroll
    for (int s = 0; s < 2; ++s) {
      int g = wave * 16 + q16;               // this wave's output col
      bf16x8 bf = ldb8(&Wc[g * 64 + (((s * 4 + quad) ^ x7) * 8)]);
#pragma unroll
      for (int rt = 0; rt < 2; ++rt) {
        int r = rt * 16 + q16;
        int p = ((s * 4 + quad) ^ (r & 7)) * 8;
        const float* ap = &Xc[r * 64 + p];
        float4 a0 = *(const float4*)ap;
        float4 a1 = *(const float4*)(ap + 4);
        Frag8 af = packA(a0, a1);
        acc[rt] = __builtin_amdgcn_mfma_f32_16x16x32_bf16(
            af.b, bf, acc[rt], 0, 0, 0);
      }
    }
    __syncthreads();                         // readers done + next stage landed
    cur ^= 1;
  }

  const int bb = rblk >> 7;                  // 128 row-blocks per batch
  const int h = wave * 16 + q16;
#pragma unroll
  for (int rt = 0; rt < 2; ++rt) {
    const int t0 = (int)(row0 - (size_t)bb * T_) + rt * 16 + quad * 4;
    if (mat == 2) {                          // V: store transposed
      ushort4 v;
      v.x = bfbits(acc[rt][0]); v.y = bfbits(acc[rt][1]);
      v.z = bfbits(acc[rt][2]); v.w = bfbits(acc[rt][3]);
      *(ushort4*)(Vt + ((size_t)bb * H_ + h) * T_ + t0) = v;
    } else {
      // Q pre-scaled by (1/sqrt(64))*log2(e) -> softmax in exp2 domain
      float scale = (mat == 0) ? 0.18033688f : 1.0f;
#pragma unroll
      for (int r = 0; r < 4; ++r) {
        size_t row = row0 + rt * 16 + quad * 4 + r;
        qkv[(size_t)mat * 1048576 + row * H_ + h] = bfbits(acc[rt][r] * scale);
      }
    }
  }
}

// ---------------- k2: flash attention, O^T formulation, zero-shuffle PV -----
// R5 structure (best measured: ~39.5 us): grid (256, ny), 4 waves, K/V 2-phase
// LDS dbuf, psi-permuted K staging so P^T B-frag is lane-local, per-lane
// alpha/l, defer-max. Added: T5 s_setprio around the MFMA clusters.
__global__ __launch_bounds__(256) void attn(const unsigned short* __restrict__ Q,
                                            const unsigned short* __restrict__ K,
                                            const unsigned short* __restrict__ Vt,
                                            float* __restrict__ part,
                                            int lgch, int nslots) {
  const int b = blockIdx.x >> 6;
  const int qblk = 63 - (blockIdx.x & 63);   // big triangles dispatch first
  const int ki = qblk + 1;                   // total 64-row k-tiles
  const int c = blockIdx.y;
  const int cst = c << lgch;
  if (cst >= ki) return;
  const int tcnt = 1 << lgch;
  const int kend = (ki < cst + tcnt) ? ki : cst + tcnt;

  __shared__ unsigned short Ks[2][4096];     // 2 x (64 slots x 64 halves) = 16 KB
  __shared__ unsigned short Vs[2][4096];     // 2 x (64 hrows x 64 halves) = 16 KB
  const int lane = threadIdx.x & 63;
  const int wave = threadIdx.x >> 6;
  const int q16 = lane & 15, quad = lane >> 4;
  const int x7 = q16 & 7;
  const int rloc = lane >> 3, cpos = lane & 7;

  const unsigned short* Qb = Q + (size_t)b * T_ * H_;
  const unsigned short* Kb = K + (size_t)b * T_ * H_;
  const unsigned short* Vtb = Vt + (size_t)b * H_ * T_;

  // K slot-row permutation: slot g holds K-row psi(g) of the tile.
  // psi(g) = 8*((g&15)>>2) + (g&3) + 4*((g>>4)&1) + 32*(g>>5)  (bijective)
  int psi_[2];
#pragma unroll
  for (int ii = 0; ii < 2; ++ii) {
    int g = (wave * 2 + ii) * 8 + rloc;
    psi_[ii] = 8 * ((g & 15) >> 2) + (g & 3) + 4 * ((g >> 4) & 1) + 32 * (g >> 5);
  }

  auto stage = [&](int buf, int kt) {
    const int kkb = kt * 64;
#pragma unroll
    for (int ii = 0; ii < 2; ++ii) {
      int i = wave * 2 + ii;
      gload16(Kb + (size_t)(kkb + psi_[ii]) * H_ + (cpos ^ rloc) * 8,
              &Ks[buf][i * 512]);
      gload16(Vtb + (size_t)(i * 8 + rloc) * T_ + kkb + (cpos ^ rloc) * 8,
              &Vs[buf][i * 512]);
    }
  };

  const int q0w = qblk * 64 + wave * 16;     // this wave's q-rows
  bf16x8 qf0 = ldb8(Qb + (size_t)(q0w + q16) * H_ + quad * 8);
  bf16x8 qf1 = ldb8(Qb + (size_t)(q0w + q16) * H_ + 32 + quad * 8);

  f32x4 o[4] = {};                           // O^T frag: h=ct*16+quad*4+r, q=q16
  float m = -3.0e38f, l = 0.0f;              // per-lane l partial (this quad)
  const int q_abs = q0w + q16;

  stage(0, cst);
  __syncthreads();                           // prologue staging visible

  int cur = 0;
  for (int kt = cst; kt < kend; ++kt) {
    const int kkb = kt * 64;
    if (kt + 1 < kend) stage(cur ^ 1, kt + 1);  // prefetch next tile
    const unsigned short* Kc = Ks[cur];
    const unsigned short* Vc = Vs[cur];

    // ---- QK^T: S^T = K Q^T (A rows = permuted K rows) ----
    f32x4 st[4];
    __builtin_amdgcn_s_setprio(1);
#pragma unroll
    for (int kb = 0; kb < 4; ++kb) {
      bf16x8 ka0 = ldb8(&Kc[(kb * 16 + q16) * 64 + ((quad ^ x7) * 8)]);
      bf16x8 ka1 = ldb8(&Kc[(kb * 16 + q16) * 64 + (((quad + 4) ^ x7) * 8)]);
      f32x4 s = {0.f, 0.f, 0.f, 0.f};
      s = __builtin_amdgcn_mfma_f32_16x16x32_bf16(ka0, qf0, s, 0, 0, 0);
      s = __builtin_amdgcn_mfma_f32_16x16x32_bf16(ka1, qf1, s, 0, 0, 0);
      st[kb] = s;
    }
    __builtin_amdgcn_s_setprio(0);
    if (kt == ki - 1) {                      // diagonal tile: causal mask
      const int kb8q = kkb + 8 * quad;       // st[kb][r] <-> k = kb8q+4(kb&1)+32(kb>>1)+r
#pragma unroll
      for (int kb = 0; kb < 4; ++kb) {
        const int kof = kb8q + 4 * (kb & 1) + 32 * (kb >> 1);
#pragma unroll
        for (int r = 0; r < 4; ++r)
          if (kof + r > q_abs) st[kb][r] = -3.0e38f;
      }
    }

    // ---- online softmax (exp2 domain, defer-max, per-lane l partials) ----
    float mloc = fmaxf(fmaxf(st[0][0], st[0][1]), fmaxf(st[0][2], st[0][3]));
#pragma unroll
    for (int kb = 1; kb < 4; ++kb)
      mloc = fmaxf(mloc, fmaxf(fmaxf(st[kb][0], st[kb][1]),
                               fmaxf(st[kb][2], st[kb][3])));
    mloc = fmaxf(mloc, __shfl_xor(mloc, 16));
    mloc = fmaxf(mloc, __shfl_xor(mloc, 32));
    const bool defer = __all(mloc - m <= 8.0f);   // wave-uniform
    const float mnew = defer ? m : fmaxf(m, mloc);
    float lsum = 0.f;
    unsigned pk[4][2];
#pragma unroll
    for (int kb = 0; kb < 4; ++kb) {
      float p0 = exp2f(st[kb][0] - mnew);
      float p1 = exp2f(st[kb][1] - mnew);
      float p2 = exp2f(st[kb][2] - mnew);
      float p3 = exp2f(st[kb][3] - mnew);
      lsum += (p0 + p1) + (p2 + p3);
      pk[kb][0] = pkbf(p0, p1);
      pk[kb][1] = pkbf(p2, p3);
    }
    if (defer) {
      l += lsum;                             // alpha == 1, no rescale
    } else {
      float alpha = exp2f(m - mnew);         // per-lane (col=q16 layout)
      l = l * alpha + lsum;
      m = mnew;
#pragma unroll
      for (int ct = 0; ct < 4; ++ct) {
        o[ct][0] *= alpha; o[ct][1] *= alpha;
        o[ct][2] *= alpha; o[ct][3] *= alpha;
      }
    }

    // ---- PV: O^T += V^T P^T; P^T B-frag lane-local (zero shuffles) ----
    __builtin_amdgcn_s_setprio(1);
#pragma unroll
    for (int ks = 0; ks < 2; ++ks) {
      Frag8 pf;
      pf.u.x = pk[2 * ks][0];
      pf.u.y = pk[2 * ks][1];
      pf.u.z = pk[2 * ks + 1][0];
      pf.u.w = pk[2 * ks + 1][1];
      int vp = ((ks * 4 + quad) ^ x7) * 8;
      bf16x8 v0 = ldb8(&Vc[(q16 + 0)  * 64 + vp]);
      bf16x8 v1 = ldb8(&Vc[(q16 + 16) * 64 + vp]);
      bf16x8 v2 = ldb8(&Vc[(q16 + 32) * 64 + vp]);
      bf16x8 v3 = ldb8(&Vc[(q16 + 48) * 64 + vp]);
      o[0] = __builtin_amdgcn_mfma_f32_16x16x32_bf16(v0, pf.b, o[0], 0, 0, 0);
      o[1] = __builtin_amdgcn_mfma_f32_16x16x32_bf16(v1, pf.b, o[1], 0, 0, 0);
      o[2] = __builtin_amdgcn_mfma_f32_16x16x32_bf16(v2, pf.b, o[2], 0, 0, 0);
      o[3] = __builtin_amdgcn_mfma_f32_16x16x32_bf16(v3, pf.b, o[3], 0, 0, 0);
    }
    __builtin_amdgcn_s_setprio(0);
    __syncthreads();                         // readers done + next stage landed
    cur ^= 1;
  }

  // ---- partial write: O^T pairs; word (ct*64+lane)*2+p packs h=..2p,2p+1 ----
  const int qtl = qblk * 4 + wave;
  float lr = l;
  lr += __shfl_xor(lr, 16);
  lr += __shfl_xor(lr, 32);
  float* Pf = part + ((size_t)((b << 8) + qtl) * nslots + c) * 544;
  unsigned* Pw = (unsigned*)Pf;
#pragma unroll
  for (int ct = 0; ct < 4; ++ct) {
    uint2 w;
    w.x = pkbf(o[ct][0], o[ct][1]);
    w.y = pkbf(o[ct][2], o[ct][3]);
    *(uint2*)&Pw[(ct * 64 + lane) * 2] = w;
  }
  if (quad == 0) { Pf[512 + q16] = m; Pf[528 + q16] = lr; }
}

// ---------------- k3: merge partials per q-tile, normalize, store ----------
// Partial O^T layout: word (ct*64 + quad*16 + q)*2 + p = bf16 pair
// (h = ct*16+quad*4+2p, h+1), col q. Thread -> (q=row, h=col0..col0+3).
__global__ __launch_bounds__(256) void attn_merge(const float* __restrict__ part,
                                                  float* __restrict__ out,
                                                  int lgch, int nslots) {
  const int qt = blockIdx.x;                 // 0..1023
  const int qtl = qt & 255, b = qt >> 8;
  const int ki = (qtl >> 2) + 1;             // 64-row k-tiles
  const int nch = (ki + (1 << lgch) - 1) >> lgch;
  const int t = threadIdx.x;
  const int row = t >> 4;                    // q 0..15
  const int col0 = (t & 15) * 4;             // h base
  const int ct = col0 >> 4;
  const int quad_s = (col0 >> 2) & 3;
  const int lane0 = quad_s * 16 + row;
  const float* P0 = part + (size_t)qt * nslots * 544;
  float M = -3.0e38f;
  for (int c2 = 0; c2 < nch; ++c2) M = fmaxf(M, P0[c2 * 544 + 512 + row]);
  float L = 0.f;
  float ax = 0.f, ay = 0.f, az = 0.f, aw = 0.f;
  for (int c2 = 0; c2 < nch; ++c2) {
    const float* P = P0 + c2 * 544;
    float wgt = exp2f(P[512 + row] - M);
    L += wgt * P[528 + row];
    const unsigned* Pww = (const unsigned*)P;
    uint2 wd = *(const uint2*)&Pww[(ct * 64 + lane0) * 2];
    ax += wgt * b2f(wd.x & 0xffffu);
    ay += wgt * b2f(wd.x >> 16);
    az += wgt * b2f(wd.y & 0xffffu);
    aw += wgt * b2f(wd.y >> 16);
  }
  float inv = 1.0f / L;
  float4 r = {ax * inv, ay * inv, az * inv, aw * inv};
  *(float4*)(out + ((size_t)b * T_ + qtl * 16 + row) * H_ + col0) = r;
}

extern "C" void kernel_launch(void* const* d_in, const int* in_sizes, int n_in,
                              void* d_out, int out_size, void* d_ws, size_t ws_size,
                              hipStream_t stream) {
  const float* x  = (const float*)d_in[0];
  const float* Wq = (const float*)d_in[1];
  const float* Wk = (const float*)d_in[2];
  const float* Wv = (const float*)d_in[3];
  float* out = (float*)d_out;
  unsigned short* ws = (unsigned short*)d_ws;

  // ws layout (ushort units):
  //   [0, 196608)           Wb  (Q|K|V bf16 weights)
  //   [196608, +2*1048576)  Q,K bf16 [B*T][64]  (Q pre-scaled, exp2 domain)
  //   next 1048576          Vt bf16 [B][64][T]
  //   next (float region)   partials: 1024 * nslots * 544 fp32 words
  unsigned short* Wb  = ws;
  unsigned short* qkv = ws + 196608;
  unsigned short* Vt  = qkv + (size_t)2 * 1048576;
  float* part = (float*)(ws + 196608 + (size_t)3 * 1048576);

  // chunk = 4 tiles (16 y-chunks, 35.7 MB partials) if workspace allows,
  // else the chunk = 8 layout (17.8 MB partials).
  const size_t base_bytes = ((size_t)196608 + (size_t)3 * 1048576) * 2;
  const size_t need16 = base_bytes + (size_t)1024 * 16 * 544 * 4;
  int lgch = 3, ny = 8, nslots = 8;
  if (ws_size >= need16) { lgch = 2; ny = 16; nslots = 16; }

  wconv<<<192, 256, 0, stream>>>(Wq, Wk, Wv, Wb);
  qkv_proj<<<1536, 256, 0, stream>>>(x, Wb, qkv, Vt);
  attn<<<dim3(256, ny), 256, 0, stream>>>(qkv, qkv + 1048576, Vt, part, lgch, nslots);
  attn_merge<<<1024, 256, 0, stream>>>(part, out, lgch, nslots);
}

// Round 9
// 163.830 us; speedup vs baseline: 1.3363x; 1.2146x over previous
//
#include <hip/hip_runtime.h>
#include <hip/hip_bf16.h>

#define B_ 4
#define T_ 4096
#define C_ 1024
#define H_ 64

typedef __bf16 bf16x8 __attribute__((ext_vector_type(8)));
typedef float f32x4 __attribute__((ext_vector_type(4)));
typedef unsigned short u16x8 __attribute__((ext_vector_type(8)));

union Frag8 { uint4 u; bf16x8 b; u16x8 s; };

__device__ inline unsigned short bfbits(float f) {
  union { __hip_bfloat16 h; unsigned short u; } cv;
  cv.h = __float2bfloat16(f);
  return cv.u;
}

__device__ inline float b2f(unsigned u) {
  union { unsigned i; float f; } c; c.i = u << 16; return c.f;
}

__device__ inline bf16x8 ldb8(const unsigned short* p) {
  Frag8 f; f.u = *(const uint4*)p; return f.b;
}

// pack two fp32 -> (bf16(a)) | (bf16(b)<<16), round-half-up, 3 VALU ops
__device__ inline unsigned pkbf(float a, float b) {
  union { float f; unsigned u; } ua, ub; ua.f = a; ub.f = b;
  return __builtin_amdgcn_perm(ub.u + 0x8000u, ua.u + 0x8000u, 0x07060302u);
}

__device__ inline Frag8 packA(float4 a0, float4 a1) {
  Frag8 af;
  af.s[0] = bfbits(a0.x); af.s[1] = bfbits(a0.y);
  af.s[2] = bfbits(a0.z); af.s[3] = bfbits(a0.w);
  af.s[4] = bfbits(a1.x); af.s[5] = bfbits(a1.y);
  af.s[6] = bfbits(a1.z); af.s[7] = bfbits(a1.w);
  return af;
}

// async global->LDS, 16B per lane; LDS dest = wave-uniform base + lane*16
__device__ inline void gload16(const void* g, void* l) {
  __builtin_amdgcn_global_load_lds(
      (const __attribute__((address_space(1))) unsigned int*)g,
      (__attribute__((address_space(3))) unsigned int*)l, 16, 0, 0);
}

// ---------------- k0: convert W (3 x [64,1024] fp32) to bf16 ----------------
__global__ __launch_bounds__(256) void wconv(const float* __restrict__ Wq,
                                             const float* __restrict__ Wk,
                                             const float* __restrict__ Wv,
                                             unsigned short* __restrict__ Wb) {
  int i = blockIdx.x * 256 + threadIdx.x;
  size_t e = (size_t)i * 4;
  const float* src = (e < 65536) ? (Wq + e)
                   : (e < 131072 ? (Wk + (e - 65536)) : (Wv + (e - 131072)));
  float4 v = *(const float4*)src;
  unsigned long long o =
      (unsigned long long)bfbits(v.x)
    | ((unsigned long long)bfbits(v.y) << 16)
    | ((unsigned long long)bfbits(v.z) << 32)
    | ((unsigned long long)bfbits(v.w) << 48);
  *(unsigned long long*)(Wb + e) = o;
}

// ---------------- k1: QKV projection GEMM, 2-phase double-buffered ----------
// R1-proven structure (512 blocks x 32 rows x 192 cols, 64 KB LDS). R8's
// per-matrix split REVERTED: it tripled HBM fetch (per-XCD L2s don't share x
// across adjacent blocks) and starved MFMA per block.
__global__ __launch_bounds__(256) void qkv_proj(const float* __restrict__ x,
                                                const unsigned short* __restrict__ Wb,
                                                unsigned short* __restrict__ qkv,
                                                unsigned short* __restrict__ Vt) {
  __shared__ float xs[2][2048];               // 2 x (32 rows x 64 f32) = 16 KB
  __shared__ unsigned short Wsh[2][12288];    // 2 x (192 rows x 64 halves) = 48 KB
  const int lane = threadIdx.x & 63;
  const int wave = threadIdx.x >> 6;
  const int q16 = lane & 15, quad = lane >> 4;
  const int x7 = q16 & 7;
  const size_t row0 = (size_t)blockIdx.x * 32;

  const int sr = lane >> 4;                  // x-staging: row within group of 4
  const int sc_pos = lane & 15;              // x-staging: stored 16B-chunk pos
  const int rloc = lane >> 3;                // W-staging: row within group of 8
  const int cpos = lane & 7;                 // W-staging: stored 16B-chunk pos

  f32x4 acc[2][3] = {};

  auto stage = [&](int buf, int kc) {
#pragma unroll
    for (int ii = 0; ii < 2; ++ii) {
      int i = wave * 2 + ii;
      int r = i * 4 + sr;
      int sg = (sc_pos >> 1) ^ (r & 7);
      const float* gp = x + (row0 + r) * C_ + kc + sg * 8 + (sc_pos & 1) * 4;
      gload16(gp, &xs[buf][i * 256]);
    }
#pragma unroll
    for (int jj = 0; jj < 6; ++jj) {
      int j = wave * 6 + jj;
      int g = j * 8 + rloc;                  // flat col 0..191
      const unsigned short* gp = Wb + (size_t)(g >> 6) * 65536
                                    + (size_t)(g & 63) * C_ + kc + (cpos ^ rloc) * 8;
      gload16(gp, &Wsh[buf][j * 512]);
    }
  };

  stage(0, 0);
  __syncthreads();                           // prologue staging visible

  int cur = 0;
  for (int t = 0; t < 16; ++t) {
    if (t < 15) stage(cur ^ 1, (t + 1) * 64);  // prefetch next chunk
    const float* Xc = xs[cur];
    const unsigned short* Wc = Wsh[cur];
#pragma unroll
    for (int s = 0; s < 2; ++s) {
      bf16x8 bf[3];
#pragma unroll
      for (int ct = 0; ct < 3; ++ct) {
        int g = wave * 48 + ct * 16 + q16;
        bf[ct] = ldb8(&Wc[g * 64 + (((s * 4 + quad) ^ x7) * 8)]);
      }
#pragma unroll
      for (int rt = 0; rt < 2; ++rt) {
        int r = rt * 16 + q16;
        int p = ((s * 4 + quad) ^ (r & 7)) * 8;
        const float* ap = &Xc[r * 64 + p];
        float4 a0 = *(const float4*)ap;
        float4 a1 = *(const float4*)(ap + 4);
        Frag8 af = packA(a0, a1);
#pragma unroll
        for (int ct = 0; ct < 3; ++ct)
          acc[rt][ct] = __builtin_amdgcn_mfma_f32_16x16x32_bf16(
              af.b, bf[ct], acc[rt][ct], 0, 0, 0);
      }
    }
    __syncthreads();                         // readers done + next stage landed
    cur ^= 1;
  }

  const int bb = (int)(blockIdx.x >> 7);     // 128 blocks per batch
#pragma unroll
  for (int rt = 0; rt < 2; ++rt) {
    const int t0 = (int)(row0 - (size_t)bb * T_) + rt * 16 + quad * 4;
#pragma unroll
    for (int ct = 0; ct < 3; ++ct) {
      int gcol = wave * 48 + ct * 16;
      int mat = gcol >> 6, h = (gcol & 63) + q16;
      if (mat == 2) {                        // V: store transposed
        ushort4 v;
        v.x = bfbits(acc[rt][ct][0]); v.y = bfbits(acc[rt][ct][1]);
        v.z = bfbits(acc[rt][ct][2]); v.w = bfbits(acc[rt][ct][3]);
        *(ushort4*)(Vt + ((size_t)bb * H_ + h) * T_ + t0) = v;
      } else {
        // Q pre-scaled by (1/sqrt(64))*log2(e) -> softmax in exp2 domain
        float scale = (mat == 0) ? 0.18033688f : 1.0f;
#pragma unroll
        for (int r = 0; r < 4; ++r) {
          size_t row = row0 + rt * 16 + quad * 4 + r;
          qkv[(size_t)mat * 1048576 + row * H_ + h] = bfbits(acc[rt][ct][r] * scale);
        }
      }
    }
  }
}

// ---------------- k2: flash attention, 3-buffer counted-vmcnt pipeline ------
// R5 compute structure (O^T zero-shuffle, defer-max, setprio) + T4: depth-2
// staging. Tile t's loads are issued 2 iterations early and waited with
// vmcnt(4) (t+1's 4 loads stay IN FLIGHT across the raw s_barrier -- never
// drain to 0 in the loop). Hazards: pre-compute barrier at top of iter t
// guarantees (a) all waves' tile-t loads landed (each wave did its own
// vmcnt(4) before the barrier) and (b) all waves finished compute(t-1), so
// staging buf (t+2)%3 (== t-1's buf) after the barrier is safe. 48 KB LDS ->
// 3 blocks/CU (12 waves/CU).
__global__ __launch_bounds__(256) void attn(const unsigned short* __restrict__ Q,
                                            const unsigned short* __restrict__ K,
                                            const unsigned short* __restrict__ Vt,
                                            float* __restrict__ part,
                                            int lgch, int nslots) {
  const int b = blockIdx.x >> 6;
  const int qblk = 63 - (blockIdx.x & 63);   // big triangles dispatch first
  const int ki = qblk + 1;                   // total 64-row k-tiles
  const int c = blockIdx.y;
  const int cst = c << lgch;
  if (cst >= ki) return;
  const int tcnt = 1 << lgch;
  const int kend = (ki < cst + tcnt) ? ki : cst + tcnt;

  __shared__ unsigned short Ks[3][4096];     // 3 x (64 slots x 64 halves) = 24 KB
  __shared__ unsigned short Vs[3][4096];     // 3 x (64 hrows x 64 halves) = 24 KB
  const int lane = threadIdx.x & 63;
  const int wave = threadIdx.x >> 6;
  const int q16 = lane & 15, quad = lane >> 4;
  const int x7 = q16 & 7;
  const int rloc = lane >> 3, cpos = lane & 7;

  const unsigned short* Qb = Q + (size_t)b * T_ * H_;
  const unsigned short* Kb = K + (size_t)b * T_ * H_;
  const unsigned short* Vtb = Vt + (size_t)b * H_ * T_;

  // K slot-row permutation: slot g holds K-row psi(g) of the tile.
  // psi(g) = 8*((g&15)>>2) + (g&3) + 4*((g>>4)&1) + 32*(g>>5)  (bijective)
  // => after S^T = K.Q^T, lane holds exactly the P^T B-fragment for
  //    O^T = V^T.P^T (no cross-lane exchange).
  int psi_[2];
#pragma unroll
  for (int ii = 0; ii < 2; ++ii) {
    int g = (wave * 2 + ii) * 8 + rloc;
    psi_[ii] = 8 * ((g & 15) >> 2) + (g & 3) + 4 * ((g >> 4) & 1) + 32 * (g >> 5);
  }

  auto stage = [&](int buf, int kt) {        // 4 gload_lds per lane
    const int kkb = kt * 64;
#pragma unroll
    for (int ii = 0; ii < 2; ++ii) {
      int i = wave * 2 + ii;
      gload16(Kb + (size_t)(kkb + psi_[ii]) * H_ + (cpos ^ rloc) * 8,
              &Ks[buf][i * 512]);
      gload16(Vtb + (size_t)(i * 8 + rloc) * T_ + kkb + (cpos ^ rloc) * 8,
              &Vs[buf][i * 512]);
    }
  };

  const int q0w = qblk * 64 + wave * 16;     // this wave's q-rows
  bf16x8 qf0 = ldb8(Qb + (size_t)(q0w + q16) * H_ + quad * 8);
  bf16x8 qf1 = ldb8(Qb + (size_t)(q0w + q16) * H_ + 32 + quad * 8);

  f32x4 o[4] = {};                           // O^T frag: h=ct*16+quad*4+r, q=q16
  float m = -3.0e38f, l = 0.0f;              // per-lane l partial (this quad)
  const int q_abs = q0w + q16;

  stage(0, cst);                             // depth-2 prologue
  if (cst + 1 < kend) stage(1, cst + 1);

  int c0 = 0;
  for (int kt = cst; kt < kend; ++kt) {
    const int kkb = kt * 64;
    // [1] wait own tile-kt loads (issued 2 iters ago); keep kt+1's in flight
    if (kt + 1 < kend) {
      asm volatile("s_waitcnt vmcnt(4)" ::: "memory");
    } else {
      asm volatile("s_waitcnt vmcnt(0)" ::: "memory");
    }
    __builtin_amdgcn_sched_barrier(0);
    // [2] rendezvous: all waves' kt loads landed; all waves past compute kt-1
    __builtin_amdgcn_s_barrier();
    // [3] stage kt+2 into the buffer tile kt-1 used (safe after barrier)
    if (kt + 2 < kend) {
      int sb = c0 + 2; if (sb >= 3) sb -= 3;
      stage(sb, kt + 2);
    }
    const unsigned short* Kc = Ks[c0];
    const unsigned short* Vc = Vs[c0];

    // ---- QK^T: S^T = K Q^T (A rows = permuted K rows) ----
    f32x4 st[4];
    __builtin_amdgcn_s_setprio(1);
#pragma unroll
    for (int kb = 0; kb < 4; ++kb) {
      bf16x8 ka0 = ldb8(&Kc[(kb * 16 + q16) * 64 + ((quad ^ x7) * 8)]);
      bf16x8 ka1 = ldb8(&Kc[(kb * 16 + q16) * 64 + (((quad + 4) ^ x7) * 8)]);
      f32x4 s = {0.f, 0.f, 0.f, 0.f};
      s = __builtin_amdgcn_mfma_f32_16x16x32_bf16(ka0, qf0, s, 0, 0, 0);
      s = __builtin_amdgcn_mfma_f32_16x16x32_bf16(ka1, qf1, s, 0, 0, 0);
      st[kb] = s;
    }
    __builtin_amdgcn_s_setprio(0);
    if (kt == ki - 1) {                      // diagonal tile: causal mask
      const int kb8q = kkb + 8 * quad;       // st[kb][r] <-> k = kb8q+4(kb&1)+32(kb>>1)+r
#pragma unroll
      for (int kb = 0; kb < 4; ++kb) {
        const int kof = kb8q + 4 * (kb & 1) + 32 * (kb >> 1);
#pragma unroll
        for (int r = 0; r < 4; ++r)
          if (kof + r > q_abs) st[kb][r] = -3.0e38f;
      }
    }

    // ---- online softmax (exp2 domain, defer-max, per-lane l partials) ----
    float mloc = fmaxf(fmaxf(st[0][0], st[0][1]), fmaxf(st[0][2], st[0][3]));
#pragma unroll
    for (int kb = 1; kb < 4; ++kb)
      mloc = fmaxf(mloc, fmaxf(fmaxf(st[kb][0], st[kb][1]),
                               fmaxf(st[kb][2], st[kb][3])));
    mloc = fmaxf(mloc, __shfl_xor(mloc, 16));
    mloc = fmaxf(mloc, __shfl_xor(mloc, 32));
    const bool defer = __all(mloc - m <= 8.0f);   // wave-uniform
    const float mnew = defer ? m : fmaxf(m, mloc);
    float lsum = 0.f;
    unsigned pk[4][2];
#pragma unroll
    for (int kb = 0; kb < 4; ++kb) {
      float p0 = exp2f(st[kb][0] - mnew);
      float p1 = exp2f(st[kb][1] - mnew);
      float p2 = exp2f(st[kb][2] - mnew);
      float p3 = exp2f(st[kb][3] - mnew);
      lsum += (p0 + p1) + (p2 + p3);
      pk[kb][0] = pkbf(p0, p1);
      pk[kb][1] = pkbf(p2, p3);
    }
    if (defer) {
      l += lsum;                             // alpha == 1, no rescale
    } else {
      float alpha = exp2f(m - mnew);         // per-lane (col=q16 layout)
      l = l * alpha + lsum;
      m = mnew;
#pragma unroll
      for (int ct = 0; ct < 4; ++ct) {
        o[ct][0] *= alpha; o[ct][1] *= alpha;
        o[ct][2] *= alpha; o[ct][3] *= alpha;
      }
    }

    // ---- PV: O^T += V^T P^T; P^T B-frag lane-local (zero shuffles) ----
    __builtin_amdgcn_s_setprio(1);
#pragma unroll
    for (int ks = 0; ks < 2; ++ks) {
      Frag8 pf;
      pf.u.x = pk[2 * ks][0];
      pf.u.y = pk[2 * ks][1];
      pf.u.z = pk[2 * ks + 1][0];
      pf.u.w = pk[2 * ks + 1][1];
      int vp = ((ks * 4 + quad) ^ x7) * 8;
      bf16x8 v0 = ldb8(&Vc[(q16 + 0)  * 64 + vp]);
      bf16x8 v1 = ldb8(&Vc[(q16 + 16) * 64 + vp]);
      bf16x8 v2 = ldb8(&Vc[(q16 + 32) * 64 + vp]);
      bf16x8 v3 = ldb8(&Vc[(q16 + 48) * 64 + vp]);
      o[0] = __builtin_amdgcn_mfma_f32_16x16x32_bf16(v0, pf.b, o[0], 0, 0, 0);
      o[1] = __builtin_amdgcn_mfma_f32_16x16x32_bf16(v1, pf.b, o[1], 0, 0, 0);
      o[2] = __builtin_amdgcn_mfma_f32_16x16x32_bf16(v2, pf.b, o[2], 0, 0, 0);
      o[3] = __builtin_amdgcn_mfma_f32_16x16x32_bf16(v3, pf.b, o[3], 0, 0, 0);
    }
    __builtin_amdgcn_s_setprio(0);
    c0 = (c0 == 2) ? 0 : c0 + 1;
  }

  // ---- partial write: O^T pairs; word (ct*64+lane)*2+p packs h=..2p,2p+1 ----
  const int qtl = qblk * 4 + wave;
  float lr = l;
  lr += __shfl_xor(lr, 16);
  lr += __shfl_xor(lr, 32);
  float* Pf = part + ((size_t)((b << 8) + qtl) * nslots + c) * 544;
  unsigned* Pw = (unsigned*)Pf;
#pragma unroll
  for (int ct = 0; ct < 4; ++ct) {
    uint2 w;
    w.x = pkbf(o[ct][0], o[ct][1]);
    w.y = pkbf(o[ct][2], o[ct][3]);
    *(uint2*)&Pw[(ct * 64 + lane) * 2] = w;
  }
  if (quad == 0) { Pf[512 + q16] = m; Pf[528 + q16] = lr; }
}

// ---------------- k3: merge partials per q-tile, normalize, store ----------
// Partial O^T layout: word (ct*64 + quad*16 + q)*2 + p = bf16 pair
// (h = ct*16+quad*4+2p, h+1), col q. Thread -> (q=row, h=col0..col0+3).
__global__ __launch_bounds__(256) void attn_merge(const float* __restrict__ part,
                                                  float* __restrict__ out,
                                                  int lgch, int nslots) {
  const int qt = blockIdx.x;                 // 0..1023
  const int qtl = qt & 255, b = qt >> 8;
  const int ki = (qtl >> 2) + 1;             // 64-row k-tiles
  const int nch = (ki + (1 << lgch) - 1) >> lgch;
  const int t = threadIdx.x;
  const int row = t >> 4;                    // q 0..15
  const int col0 = (t & 15) * 4;             // h base
  const int ct = col0 >> 4;
  const int quad_s = (col0 >> 2) & 3;
  const int lane0 = quad_s * 16 + row;
  const float* P0 = part + (size_t)qt * nslots * 544;
  float M = -3.0e38f;
  for (int c2 = 0; c2 < nch; ++c2) M = fmaxf(M, P0[c2 * 544 + 512 + row]);
  float L = 0.f;
  float ax = 0.f, ay = 0.f, az = 0.f, aw = 0.f;
  for (int c2 = 0; c2 < nch; ++c2) {
    const float* P = P0 + c2 * 544;
    float wgt = exp2f(P[512 + row] - M);
    L += wgt * P[528 + row];
    const unsigned* Pww = (const unsigned*)P;
    uint2 wd = *(const uint2*)&Pww[(ct * 64 + lane0) * 2];
    ax += wgt * b2f(wd.x & 0xffffu);
    ay += wgt * b2f(wd.x >> 16);
    az += wgt * b2f(wd.y & 0xffffu);
    aw += wgt * b2f(wd.y >> 16);
  }
  float inv = 1.0f / L;
  float4 r = {ax * inv, ay * inv, az * inv, aw * inv};
  *(float4*)(out + ((size_t)b * T_ + qtl * 16 + row) * H_ + col0) = r;
}

extern "C" void kernel_launch(void* const* d_in, const int* in_sizes, int n_in,
                              void* d_out, int out_size, void* d_ws, size_t ws_size,
                              hipStream_t stream) {
  const float* x  = (const float*)d_in[0];
  const float* Wq = (const float*)d_in[1];
  const float* Wk = (const float*)d_in[2];
  const float* Wv = (const float*)d_in[3];
  float* out = (float*)d_out;
  unsigned short* ws = (unsigned short*)d_ws;

  // ws layout (ushort units):
  //   [0, 196608)           Wb  (Q|K|V bf16 weights)
  //   [196608, +2*1048576)  Q,K bf16 [B*T][64]  (Q pre-scaled, exp2 domain)
  //   next 1048576          Vt bf16 [B][64][T]
  //   next (float region)   partials: 1024 * nslots * 544 fp32 words
  unsigned short* Wb  = ws;
  unsigned short* qkv = ws + 196608;
  unsigned short* Vt  = qkv + (size_t)2 * 1048576;
  float* part = (float*)(ws + 196608 + (size_t)3 * 1048576);

  // chunk = 4 tiles (16 y-chunks, 35.7 MB partials) if workspace allows,
  // else the chunk = 8 layout (17.8 MB partials).
  const size_t base_bytes = ((size_t)196608 + (size_t)3 * 1048576) * 2;
  const size_t need16 = base_bytes + (size_t)1024 * 16 * 544 * 4;
  int lgch = 3, ny = 8, nslots = 8;
  if (ws_size >= need16) { lgch = 2; ny = 16; nslots = 16; }

  wconv<<<192, 256, 0, stream>>>(Wq, Wk, Wv, Wb);
  qkv_proj<<<512, 256, 0, stream>>>(x, Wb, qkv, Vt);
  attn<<<dim3(256, ny), 256, 0, stream>>>(qkv, qkv + 1048576, Vt, part, lgch, nslots);
  attn_merge<<<1024, 256, 0, stream>>>(part, out, lgch, nslots);
}